// Round 14
// baseline (634.643 us; speedup 1.0000x reference)
//
#include <hip/hip_runtime.h>

// SparseGraphConv: y = W @ concat([x, A1x, A1^2 x, A2 x, A2^2 x]) + b
// B=16, C=64, N=2048, T=12, C_OUT=64.
//
// W/A commutation (R11 numerics, verified):  y[o,n,b,t] = z0 + sum_{k=1..4,m} A_k[n,m] z_k[o,m,b,t]
// with z_k = W_k @ x. R11's failure was the Z scatter-write; fixed by block-K layout:
//   Zm[mblk][j][32 B]  (zpack writes 768x32 B contiguous; GEMM B-stage gathers per-lane)
//   1. cvt_a:   A1,A2 -> Ahat4[n][K'] fp4(x8192) k=1,3 slots + a1p4/a2p4 + a1t4/a2t4
//   2. gemm_f4(z=2): A1^2, A2^2 (fp4) -> a2sq bf16
//   3. pack_a2: a2sq -> Ahat4 k=2,4 slots
//   4. zpack:   x -> z0 bf16 [m][j] + Zm fp4 (z*4); j = bl*768 + o*12 + t;
//               K' = mblk*64 + (k-1)*16 + ml (byte (k-1)*8+ml/2 within 32-B chunk)
//   5. gemm_f4y: y = (Ahat4 @ Z^T)/32768 + z0 + bias  (M=2048, N=Gb*768, K=8192),
//               2D XCD chunk swizzle, per-lane gather staging for B.

typedef __attribute__((ext_vector_type(8))) __bf16 bf16x8;
typedef __attribute__((ext_vector_type(4))) float f32x4;
typedef __attribute__((ext_vector_type(4))) int i32x4;
typedef __attribute__((ext_vector_type(8))) int i32x8;
typedef __attribute__((ext_vector_type(8))) unsigned short u16x8;
typedef unsigned short u16;
typedef unsigned int u32;
typedef unsigned char u8;

__device__ __forceinline__ u16 f2bf(float f) {
    u32 u = __float_as_uint(f);
    u32 r = u + 0x7FFFu + ((u >> 16) & 1u);   // round-to-nearest-even
    return (u16)(r >> 16);
}

__device__ __forceinline__ float bf2f(u16 v) {
    return __uint_as_float((u32)v << 16);
}

// e2m1 nibble encode, round-to-nearest; levels {0,.5,1,1.5,2,3,4,6}
__device__ __forceinline__ u32 f2fp4(float f) {
    u32 s = (__float_as_uint(f) >> 31) << 3;
    float m = fabsf(f);
    u32 c;
    if      (m < 0.25f) c = 0;
    else if (m < 0.75f) c = 1;
    else if (m < 1.25f) c = 2;
    else if (m < 1.75f) c = 3;
    else if (m < 2.5f)  c = 4;
    else if (m < 3.5f)  c = 5;
    else if (m < 5.0f)  c = 6;
    else                c = 7;
    return s | c;
}

__device__ __forceinline__ void gload16(const void* g, void* l) {
    __builtin_amdgcn_global_load_lds((const __attribute__((address_space(1))) void*)g,
                                     (__attribute__((address_space(3))) void*)l, 16, 0, 0);
}

__device__ __forceinline__ i32x8 up8(i32x4 v) {
    i32x8 r = {v[0], v[1], v[2], v[3], 0, 0, 0, 0};
    return r;
}

#define ASCALE 8192.f
#define ZSCALE 4.f

// ---------------------------------------------------------------------------
__global__ __launch_bounds__(256)
void cvt_w_kernel(const float* __restrict__ W, u16* __restrict__ wbf) {
    int i = blockIdx.x * 256 + threadIdx.x;
    if (i < 5 * 64 * 64) {
        int c = i & 63;
        int o = (i >> 6) & 63;
        int k = i >> 12;
        wbf[i] = f2bf(W[o * 320 + k * 64 + c]);
    }
}

// ---------------------------------------------------------------------------
// A1,A2 f32 -> Ahat4[n][K'] (k=1: koff 0, k=3: koff 16 within 32-B mblk chunk)
//           -> plain a1p4/a2p4 + transposed a1t4/a2t4 (A^2 GEMM operands)
__global__ __launch_bounds__(256)
void cvt_a_kernel(const float* __restrict__ A1, const float* __restrict__ A2,
                  u8* __restrict__ ahat4, u8* __restrict__ a1p4, u8* __restrict__ a2p4,
                  u8* __restrict__ a1t4, u8* __restrict__ a2t4) {
    __shared__ float lt[64][65];
    int bid = blockIdx.x;
    int mat = bid >> 10;
    int ti = bid & 1023;
    int tr = (ti >> 5) << 6;
    int tc = (ti & 31) << 6;
    const float* src = mat ? A2 : A1;
    u8* dstP = mat ? a2p4 : a1p4;
    u8* dstT = mat ? a2t4 : a1t4;
    const int koff = mat ? 16 : 0;
    int tid = threadIdx.x;
    int rr = tid >> 4;
    int cc = (tid & 15) << 2;
#pragma unroll
    for (int p = 0; p < 4; ++p) {
        int row = p * 16 + rr;
        int n = tr + row, m = tc + cc;
        float4 v = *(const float4*)&src[(size_t)n * 2048 + m];
        u16 w4 = (u16)(f2fp4(v.x * ASCALE) | (f2fp4(v.y * ASCALE) << 4) |
                       (f2fp4(v.z * ASCALE) << 8) | (f2fp4(v.w * ASCALE) << 12));
        *(u16*)&dstP[(size_t)n * 1024 + (m >> 1)] = w4;
        *(u16*)&ahat4[(size_t)n * 4096 + ((m >> 4) << 5) + koff + ((m & 15) >> 1)] = w4;
        lt[row][cc + 0] = v.x; lt[row][cc + 1] = v.y;
        lt[row][cc + 2] = v.z; lt[row][cc + 3] = v.w;
    }
    __syncthreads();
#pragma unroll
    for (int p = 0; p < 4; ++p) {
        int row = p * 16 + rr;
        u16 w4 = (u16)(f2fp4(lt[cc + 0][row] * ASCALE) |
                       (f2fp4(lt[cc + 1][row] * ASCALE) << 4) |
                       (f2fp4(lt[cc + 2][row] * ASCALE) << 8) |
                       (f2fp4(lt[cc + 3][row] * ASCALE) << 12));
        *(u16*)&dstT[(size_t)(tc + row) * 1024 + ((tr + cc) >> 1)] = w4;
    }
}

// ---------------------------------------------------------------------------
// a2sq bf16 [4096][2048] (A1^2 ; A2^2) -> Ahat4 k=2 (koff 8) / k=4 (koff 24)
__global__ __launch_bounds__(256)
void pack_a2_kernel(const u16* __restrict__ a2sq, u8* __restrict__ ahat4) {
    int i = blockIdx.x * 256 + threadIdx.x;
    int e = i << 3;
    int r = e >> 11, c = e & 2047;
    const u16* s = a2sq + ((size_t)r << 11) + c;
    u16x8 v = *(const u16x8*)s;
    u32 w = 0;
#pragma unroll
    for (int j = 0; j < 8; ++j)
        w |= f2fp4(bf2f(v[j]) * ASCALE) << (4 * j);
    int n = r & 2047;
    int koff = (r < 2048) ? 8 : 24;
    *(u32*)&ahat4[(size_t)n * 4096 + ((c >> 4) << 5) + koff + ((c & 15) >> 1)] = w;
}

// ---------------------------------------------------------------------------
// zpack: block = (mblk of 16 nodes m, one batch b). R11-verified conv MFMA core.
//   k=0: z0[m0+ml][bl*768 + o*12 + t] bf16
//   k=1..4: Zm[(mblk*ldj + bl*768 + j)*32 + (k-1)*8 + ml/2]  (32 B/thread contiguous)
__global__ __launch_bounds__(256, 2)
void zpack_kernel(const float* __restrict__ x, const u16* __restrict__ wbf,
                  u8* __restrict__ Zm, u16* __restrict__ z0, int b0, int ldz) {
    __shared__ u16 lh[192 * 72];    // [jj=(ml*12+t)][c]
    __shared__ u16 zt[16 * 770];    // [ml][o*12+t], stride 770 (385 words == 1 mod 32)
    const int m0 = blockIdx.x << 4;
    const int bl = blockIdx.y;
    const int b = b0 + bl;
    const int tid = threadIdx.x;
    const int w = tid >> 6, l = tid & 63;

    // stage x -> lh bf16 (16 lanes x 48-B = 768-B contiguous runs)
    {
        int ml = tid & 15;
        int c = tid >> 4;
#pragma unroll
        for (int p = 0; p < 4; ++p, c += 16) {
            const float* src = x + ((size_t)(b * 64 + c) * 2048 + m0 + ml) * 12;
            float4 v0 = *(const float4*)(src + 0);
            float4 v1 = *(const float4*)(src + 4);
            float4 v2 = *(const float4*)(src + 8);
            float vv[12];
            *(float4*)&vv[0] = v0; *(float4*)&vv[4] = v1; *(float4*)&vv[8] = v2;
            u16* d = &lh[(ml * 12) * 72 + c];
#pragma unroll
            for (int t = 0; t < 12; ++t) d[t * 72] = f2bf(vv[t]);
        }
    }
    __syncthreads();

    uint2 zr0, zr1, zr2, zr3;       // j = tid
    uint2 zs0, zs1, zs2, zs3;       // j = tid + 256
    uint2 zu0, zu1, zu2, zu3;       // j = tid + 512

#pragma unroll
    for (int k = 0; k < 5; ++k) {
        f32x4 acc[4][3] = {};
#pragma unroll
        for (int kk = 0; kk < 2; ++kk) {
            bf16x8 wf[4], hf[3];
#pragma unroll
            for (int i = 0; i < 4; ++i)
                wf[i] = *(const bf16x8*)&wbf[(size_t)(k * 64 + i * 16 + (l & 15)) * 64 + kk * 32 + (l >> 4) * 8];
#pragma unroll
            for (int j = 0; j < 3; ++j)
                hf[j] = *(const bf16x8*)&lh[(w * 48 + j * 16 + (l & 15)) * 72 + kk * 32 + (l >> 4) * 8];
#pragma unroll
            for (int i = 0; i < 4; ++i)
#pragma unroll
                for (int j = 0; j < 3; ++j)
                    acc[i][j] = __builtin_amdgcn_mfma_f32_16x16x32_bf16(wf[i], hf[j], acc[i][j], 0, 0, 0);
        }
        __syncthreads();
        {
            const int lr = (l >> 4) * 4, lc = l & 15;
#pragma unroll
            for (int j = 0; j < 3; ++j) {
                int jj = w * 48 + j * 16 + lc;
                int ml = jj / 12, t = jj - ml * 12;
#pragma unroll
                for (int i = 0; i < 4; ++i)
#pragma unroll
                    for (int q = 0; q < 4; ++q)
                        zt[ml * 770 + (i * 16 + lr + q) * 12 + t] = f2bf(acc[i][j][q]);
            }
        }
        __syncthreads();
        if (k == 0) {
            for (int it = tid; it < 1536; it += 256) {   // 16 ml x 96 x (8 u16)
                int ml = it / 96, ch = it - ml * 96;
                *(u16x8*)&z0[(size_t)(m0 + ml) * ldz + bl * 768 + ch * 8] =
                    *(const u16x8*)&zt[ml * 770 + ch * 8];
            }
        } else {
#pragma unroll
            for (int jq = 0; jq < 3; ++jq) {
                int j = jq * 256 + tid;
                u32 lo = 0, hi = 0;
#pragma unroll
                for (int mp = 0; mp < 8; ++mp) {
                    u32 a = f2fp4(bf2f(zt[(2 * mp) * 770 + j]) * ZSCALE);
                    u32 bq = f2fp4(bf2f(zt[(2 * mp + 1) * 770 + j]) * ZSCALE);
                    u32 nib = a | (bq << 4);
                    if (mp < 4) lo |= nib << (8 * mp);
                    else        hi |= nib << (8 * (mp - 4));
                }
                uint2 v; v.x = lo; v.y = hi;
                if (jq == 0) { if (k == 1) zr0 = v; else if (k == 2) zr1 = v; else if (k == 3) zr2 = v; else zr3 = v; }
                if (jq == 1) { if (k == 1) zs0 = v; else if (k == 2) zs1 = v; else if (k == 3) zs2 = v; else zs3 = v; }
                if (jq == 2) { if (k == 1) zu0 = v; else if (k == 2) zu1 = v; else if (k == 3) zu2 = v; else zu3 = v; }
            }
        }
    }
    // Zm write: 32 B per thread, consecutive threads contiguous (768x32 B per block)
    {
        size_t base = ((size_t)blockIdx.x * ldz + bl * 768) * 32;
        u8* d0 = Zm + base + (size_t)tid * 32;
        ((uint2*)d0)[0] = zr0; ((uint2*)d0)[1] = zr1; ((uint2*)d0)[2] = zr2; ((uint2*)d0)[3] = zr3;
        u8* d1 = Zm + base + (size_t)(256 + tid) * 32;
        ((uint2*)d1)[0] = zs0; ((uint2*)d1)[1] = zs1; ((uint2*)d1)[2] = zs2; ((uint2*)d1)[3] = zs3;
        u8* d2 = Zm + base + (size_t)(512 + tid) * 32;
        ((uint2*)d2)[0] = zu0; ((uint2*)d2)[1] = zu1; ((uint2*)d2)[2] = zu2; ((uint2*)d2)[3] = zu3;
    }
}

// ---------------------------------------------------------------------------
// 128^2-tile MX-fp4 GEMM, bf16 out (A^2 path; R9-R13 verified).
__global__ __launch_bounds__(256, 4)
void gemm_f4_kernel(const u8* __restrict__ A0, const u8* __restrict__ B0, u16* __restrict__ C0,
                    const u8* __restrict__ A1p, const u8* __restrict__ B1p, u16* __restrict__ C1p,
                    int Kb, int lda, int ldb, int ldc, float oscale) {
    const u8* A  = blockIdx.z ? A1p : A0;
    const u8* BT = blockIdx.z ? B1p : B0;
    u16* C       = blockIdx.z ? C1p : C0;

    __shared__ u8 lA[128 * 128];
    __shared__ u8 lB[128 * 128];

    int gx = gridDim.x;
    int nwg = gx * gridDim.y;
    int orig = blockIdx.y * gx + blockIdx.x;
    int swz = (orig & 7) * (nwg >> 3) + (orig >> 3);
    int by = swz / gx, bx = swz - by * gx;

    const int m0 = by * 128, n0 = bx * 128;
    const int tid = threadIdx.x;
    const int w = tid >> 6, l = tid & 63;
    const int wr = w >> 1, wc = w & 1;

    f32x4 acc[4][4] = {};

    const int srow = l >> 3;
    const int scol = ((l & 7) ^ srow) << 4;

    for (int kt = 0; kt < Kb; kt += 128) {
#pragma unroll
        for (int r = 0; r < 4; ++r) {
            int s = w * 4 + r;
            int row = s * 8 + srow;
            gload16(A + (size_t)(m0 + row) * lda + kt + scol, &lA[s * 1024]);
        }
#pragma unroll
        for (int r = 0; r < 4; ++r) {
            int s = w * 4 + r;
            int row = s * 8 + srow;
            gload16(BT + (size_t)(n0 + row) * ldb + kt + scol, &lB[s * 1024]);
        }
        __syncthreads();
#pragma unroll
        for (int kk = 0; kk < 2; ++kk) {
            i32x4 af[4], bfr[4];
            const int slot = kk * 4 + (l >> 4);
#pragma unroll
            for (int i = 0; i < 4; ++i) {
                int r = wr * 64 + i * 16 + (l & 15);
                af[i] = *(const i32x4*)&lA[(size_t)r * 128 + ((slot ^ (r & 7)) << 4)];
            }
#pragma unroll
            for (int j = 0; j < 4; ++j) {
                int r = wc * 64 + j * 16 + (l & 15);
                bfr[j] = *(const i32x4*)&lB[(size_t)r * 128 + ((slot ^ (r & 7)) << 4)];
            }
#pragma unroll
            for (int i = 0; i < 4; ++i)
#pragma unroll
                for (int j = 0; j < 4; ++j)
                    acc[i][j] = __builtin_amdgcn_mfma_scale_f32_16x16x128_f8f6f4(
                        up8(af[i]), up8(bfr[j]), acc[i][j], 4, 4, 0, 0x7F7F7F7F, 0, 0x7F7F7F7F);
        }
        __syncthreads();
    }

    const int lr = (l >> 4) * 4, lc = l & 15;
#pragma unroll
    for (int i = 0; i < 4; ++i) {
        int row = m0 + wr * 64 + i * 16 + lr;
#pragma unroll
        for (int j = 0; j < 4; ++j) {
            int col = n0 + wc * 64 + j * 16 + lc;
            u16* p = C + (size_t)row * ldc + col;
#pragma unroll
            for (int q = 0; q < 4; ++q)
                p[(size_t)q * ldc] = f2bf(acc[i][j][q] * oscale);
        }
    }
}

// ---------------------------------------------------------------------------
// Main GEMM with fused y epilogue: y = acc/32768 + z0 + bias.
// M=2048 (nodes), N=Gb*768 (j=bl*768+o*12+t), K=8192 (Kb=4096 A-bytes).
// B operand gathered from Zm block-K layout; 2D XCD chunk swizzle.
__global__ __launch_bounds__(256, 4)
void gemm_f4y_kernel(const u8* __restrict__ A, const u8* __restrict__ Zm,
                     const u16* __restrict__ z0, const float* __restrict__ bias,
                     float* __restrict__ y, int Kb, int lda, int ldj, int b0) {
    __shared__ u8 lA[128 * 128];
    __shared__ u8 lB[128 * 128];

    int gx = gridDim.x, gy = gridDim.y;
    int nwg = gx * gy;
    int orig = blockIdx.y * gx + blockIdx.x;
    int bx, by;
    if ((gx & 3) == 0 && (gy & 1) == 0) {
        int wx = gx >> 2, wy = gy >> 1;
        int xcd = orig & 7;
        int idx = orig >> 3;
        bx = (xcd & 3) * wx + idx % wx;
        by = (xcd >> 2) * wy + idx / wx;
    } else {
        int swz = (orig & 7) * (nwg >> 3) + (orig >> 3);
        by = swz / gx; bx = swz - by * gx;
    }

    const int m0 = by * 128, n0 = bx * 128;
    const int tid = threadIdx.x;
    const int w = tid >> 6, l = tid & 63;
    const int wr = w >> 1, wc = w & 1;

    f32x4 acc[4][4] = {};

    const int srow = l >> 3;
    const int scol = ((l & 7) ^ srow) << 4;
    const int mloc = scol >> 5;            // 0..3: mblk offset within K-tile
    const int half = scol & 16;            // 0 or 16 B within the 32-B chunk

    for (int kt = 0; kt < Kb; kt += 128) {
        const int ktm = kt >> 5;           // global mblk base of this K-tile
#pragma unroll
        for (int r = 0; r < 4; ++r) {
            int s = w * 4 + r;
            int row = s * 8 + srow;
            gload16(A + (size_t)(m0 + row) * lda + kt + scol, &lA[s * 1024]);
        }
#pragma unroll
        for (int r = 0; r < 4; ++r) {
            int s = w * 4 + r;
            int row = s * 8 + srow;
            gload16(Zm + ((size_t)(ktm + mloc) * ldj + (n0 + row)) * 32 + half, &lB[s * 1024]);
        }
        __syncthreads();
#pragma unroll
        for (int kk = 0; kk < 2; ++kk) {
            i32x4 af[4], bfr[4];
            const int slot = kk * 4 + (l >> 4);
#pragma unroll
            for (int i = 0; i < 4; ++i) {
                int r = wr * 64 + i * 16 + (l & 15);
                af[i] = *(const i32x4*)&lA[(size_t)r * 128 + ((slot ^ (r & 7)) << 4)];
            }
#pragma unroll
            for (int j = 0; j < 4; ++j) {
                int r = wc * 64 + j * 16 + (l & 15);
                bfr[j] = *(const i32x4*)&lB[(size_t)r * 128 + ((slot ^ (r & 7)) << 4)];
            }
#pragma unroll
            for (int i = 0; i < 4; ++i)
#pragma unroll
                for (int j = 0; j < 4; ++j)
                    acc[i][j] = __builtin_amdgcn_mfma_scale_f32_16x16x128_f8f6f4(
                        up8(af[i]), up8(bfr[j]), acc[i][j], 4, 4, 0, 0x7F7F7F7F, 0, 0x7F7F7F7F);
        }
        __syncthreads();
    }

    // epilogue: y[(b,o)][row*12+t] = acc/32768 + z0[row][col] + bias[o]
    const int lr = (l >> 4) * 4, lc = l & 15;
    const float os = 1.f / 32768.f;
#pragma unroll
    for (int j = 0; j < 4; ++j) {
        int col = n0 + wc * 64 + j * 16 + lc;
        int blv = col / 768;
        int r = col - blv * 768;
        int o = r / 12;
        int t = r - o * 12;
        float bv = bias[o];
        float* yb = y + ((size_t)((b0 + blv) * 64 + o) * 2048) * 12 + t;
#pragma unroll
        for (int i = 0; i < 4; ++i) {
            int row = m0 + wr * 64 + i * 16 + lr;
#pragma unroll
            for (int q = 0; q < 4; ++q) {
                float v = acc[i][j][q] * os + bf2f(z0[(size_t)(row + q) * ldj + col]) + bv;
                yb[(size_t)(row + q) * 12] = v;
            }
        }
    }
}

// ---------------------------------------------------------------------------
extern "C" void kernel_launch(void* const* d_in, const int* in_sizes, int n_in,
                              void* d_out, int out_size, void* d_ws, size_t ws_size,
                              hipStream_t stream) {
    (void)in_sizes; (void)n_in; (void)out_size;
    const float* x  = (const float*)d_in[0];
    const float* A1 = (const float*)d_in[1];
    const float* A2 = (const float*)d_in[2];
    const float* W  = (const float*)d_in[3];
    const float* bs = (const float*)d_in[4];
    float* y = (float*)d_out;
    char* ws = (char*)d_ws;

    // workspace:
    //   [0, 8.39M)    Ahat4 fp4 [2048][4096 B] (A_k x8192, K'-interleaved)
    //   [8.39M,+64K)  Wbf
    //   [CHUNK_OFF)   transient a1p4,a2p4,a1t4,a2t4 (4x2.1M) + a2sq bf16 (16.8M),
    //                 then per-chunk: Zm fp4 [128 mblk][Gb*768][32 B] | z0 bf16 [2048][Gb*768]
    const size_t CHUNK_OFF = 8454144;
    u8* ahat4 = (u8*)ws;
    u16* wbf = (u16*)(ws + 8388608);
    u8* a1p4 = (u8*)(ws + CHUNK_OFF);
    u8* a2p4 = a1p4 + (size_t)2048 * 1024;
    u8* a1t4 = a2p4 + (size_t)2048 * 1024;
    u8* a2t4 = a1t4 + (size_t)2048 * 1024;
    u16* a2sq = (u16*)(a2t4 + (size_t)2048 * 1024);   // [4096][2048] bf16

    // per-chunk bytes: Zm Gb*3145728 + z0 Gb*3145728
    size_t avail = ws_size > CHUNK_OFF ? ws_size - CHUNK_OFF : 0;
    int Gb = 16;
    while (Gb > 1 && (size_t)Gb * 6291456 > avail) Gb >>= 1;
    int ldj = Gb * 768;
    u8* Zm  = (u8*)(ws + CHUNK_OFF);
    u16* z0 = (u16*)(Zm + (size_t)128 * ldj * 32);

    cvt_w_kernel<<<80, 256, 0, stream>>>(W, wbf);
    cvt_a_kernel<<<2048, 256, 0, stream>>>(A1, A2, ahat4, a1p4, a2p4, a1t4, a2t4);

    // A1^2, A2^2 in fp4 (dual launch); acc = A^2 * 2^26 -> bf16 * 2^-26
    gemm_f4_kernel<<<dim3(16, 16, 2), 256, 0, stream>>>(
        a1p4, a1t4, a2sq,
        a2p4, a2t4, a2sq + (size_t)2048 * 2048,
        1024, 1024, 1024, 2048, 1.f / 67108864.f);
    pack_a2_kernel<<<4096, 256, 0, stream>>>(a2sq, ahat4);

    for (int b0 = 0; b0 < 16; b0 += Gb) {
        zpack_kernel<<<dim3(128, Gb), 256, 0, stream>>>(x, wbf, Zm, z0, b0, ldj);
        gemm_f4y_kernel<<<dim3(Gb * 6, 16), 256, 0, stream>>>(
            ahat4, Zm, z0, bs, y, 4096, 4096, ldj, b0);
    }
}

// Round 15
// 351.481 us; speedup vs baseline: 1.8056x; 1.8056x over previous
//
#include <hip/hip_runtime.h>

// SparseGraphConv: y = W @ concat([x, A1x, A1^2 x, A2 x, A2^2 x]) + b
// B=16, C=64, N=2048, T=12, C_OUT=64.
//
// W/A commutation:  y[o,n,b,t] = z0 + sum_{k=1..4,m} A_k[n,m] z_k[o,m,b,t], z_k = W_k @ x.
//   Zm[mblk][j][32 B] block-K layout (R14-verified gather contract).
//   R15 fix: zpack accumulates the 4 k-planes in LDS (zq) instead of 24 uint2
//   REGISTERS -- R11/R14's 480 us was a VGPR-cap (128 @ launch_bounds(256,2))
//   scratch spill (420 MB phantom WRITE_SIZE), not a write-coalescing problem.
//   1. cvt_a:   A1,A2 -> Ahat4[n][K'] fp4(x8192) k=1,3 slots + a1p4/a2p4 + a1t4/a2t4
//   2. gemm_f4(z=2): A1^2, A2^2 (fp4) -> a2sq bf16
//   3. pack_a2: a2sq -> Ahat4 k=2,4 slots
//   4. zpack:   x -> z0 bf16 [m][j] + Zm fp4 (z*4); j = bl*768 + o*12 + t
//   5. gemm_f4y: y = (Ahat4 @ Z^T)/32768 + z0 + bias  (M=2048, N=Gb*768, K=8192)

typedef __attribute__((ext_vector_type(8))) __bf16 bf16x8;
typedef __attribute__((ext_vector_type(4))) float f32x4;
typedef __attribute__((ext_vector_type(4))) int i32x4;
typedef __attribute__((ext_vector_type(8))) int i32x8;
typedef __attribute__((ext_vector_type(8))) unsigned short u16x8;
typedef unsigned short u16;
typedef unsigned int u32;
typedef unsigned char u8;

__device__ __forceinline__ u16 f2bf(float f) {
    u32 u = __float_as_uint(f);
    u32 r = u + 0x7FFFu + ((u >> 16) & 1u);   // round-to-nearest-even
    return (u16)(r >> 16);
}

__device__ __forceinline__ float bf2f(u16 v) {
    return __uint_as_float((u32)v << 16);
}

// e2m1 nibble encode, round-to-nearest; levels {0,.5,1,1.5,2,3,4,6}
__device__ __forceinline__ u32 f2fp4(float f) {
    u32 s = (__float_as_uint(f) >> 31) << 3;
    float m = fabsf(f);
    u32 c;
    if      (m < 0.25f) c = 0;
    else if (m < 0.75f) c = 1;
    else if (m < 1.25f) c = 2;
    else if (m < 1.75f) c = 3;
    else if (m < 2.5f)  c = 4;
    else if (m < 3.5f)  c = 5;
    else if (m < 5.0f)  c = 6;
    else                c = 7;
    return s | c;
}

__device__ __forceinline__ void gload16(const void* g, void* l) {
    __builtin_amdgcn_global_load_lds((const __attribute__((address_space(1))) void*)g,
                                     (__attribute__((address_space(3))) void*)l, 16, 0, 0);
}

__device__ __forceinline__ i32x8 up8(i32x4 v) {
    i32x8 r = {v[0], v[1], v[2], v[3], 0, 0, 0, 0};
    return r;
}

#define ASCALE 8192.f
#define ZSCALE 4.f

// ---------------------------------------------------------------------------
__global__ __launch_bounds__(256)
void cvt_w_kernel(const float* __restrict__ W, u16* __restrict__ wbf) {
    int i = blockIdx.x * 256 + threadIdx.x;
    if (i < 5 * 64 * 64) {
        int c = i & 63;
        int o = (i >> 6) & 63;
        int k = i >> 12;
        wbf[i] = f2bf(W[o * 320 + k * 64 + c]);
    }
}

// ---------------------------------------------------------------------------
// A1,A2 f32 -> Ahat4[n][K'] (k=1: koff 0, k=3: koff 16 within 32-B mblk chunk)
//           -> plain a1p4/a2p4 + transposed a1t4/a2t4 (A^2 GEMM operands)
__global__ __launch_bounds__(256)
void cvt_a_kernel(const float* __restrict__ A1, const float* __restrict__ A2,
                  u8* __restrict__ ahat4, u8* __restrict__ a1p4, u8* __restrict__ a2p4,
                  u8* __restrict__ a1t4, u8* __restrict__ a2t4) {
    __shared__ float lt[64][65];
    int bid = blockIdx.x;
    int mat = bid >> 10;
    int ti = bid & 1023;
    int tr = (ti >> 5) << 6;
    int tc = (ti & 31) << 6;
    const float* src = mat ? A2 : A1;
    u8* dstP = mat ? a2p4 : a1p4;
    u8* dstT = mat ? a2t4 : a1t4;
    const int koff = mat ? 16 : 0;
    int tid = threadIdx.x;
    int rr = tid >> 4;
    int cc = (tid & 15) << 2;
#pragma unroll
    for (int p = 0; p < 4; ++p) {
        int row = p * 16 + rr;
        int n = tr + row, m = tc + cc;
        float4 v = *(const float4*)&src[(size_t)n * 2048 + m];
        u16 w4 = (u16)(f2fp4(v.x * ASCALE) | (f2fp4(v.y * ASCALE) << 4) |
                       (f2fp4(v.z * ASCALE) << 8) | (f2fp4(v.w * ASCALE) << 12));
        *(u16*)&dstP[(size_t)n * 1024 + (m >> 1)] = w4;
        *(u16*)&ahat4[(size_t)n * 4096 + ((m >> 4) << 5) + koff + ((m & 15) >> 1)] = w4;
        lt[row][cc + 0] = v.x; lt[row][cc + 1] = v.y;
        lt[row][cc + 2] = v.z; lt[row][cc + 3] = v.w;
    }
    __syncthreads();
#pragma unroll
    for (int p = 0; p < 4; ++p) {
        int row = p * 16 + rr;
        u16 w4 = (u16)(f2fp4(lt[cc + 0][row] * ASCALE) |
                       (f2fp4(lt[cc + 1][row] * ASCALE) << 4) |
                       (f2fp4(lt[cc + 2][row] * ASCALE) << 8) |
                       (f2fp4(lt[cc + 3][row] * ASCALE) << 12));
        *(u16*)&dstT[(size_t)(tc + row) * 1024 + ((tr + cc) >> 1)] = w4;
    }
}

// ---------------------------------------------------------------------------
// a2sq bf16 [4096][2048] (A1^2 ; A2^2) -> Ahat4 k=2 (koff 8) / k=4 (koff 24)
__global__ __launch_bounds__(256)
void pack_a2_kernel(const u16* __restrict__ a2sq, u8* __restrict__ ahat4) {
    int i = blockIdx.x * 256 + threadIdx.x;
    int e = i << 3;
    int r = e >> 11, c = e & 2047;
    const u16* s = a2sq + ((size_t)r << 11) + c;
    u16x8 v = *(const u16x8*)s;
    u32 w = 0;
#pragma unroll
    for (int j = 0; j < 8; ++j)
        w |= f2fp4(bf2f(v[j]) * ASCALE) << (4 * j);
    int n = r & 2047;
    int koff = (r < 2048) ? 8 : 24;
    *(u32*)&ahat4[(size_t)n * 4096 + ((c >> 4) << 5) + koff + ((c & 15) >> 1)] = w;
}

// ---------------------------------------------------------------------------
// zpack: block = (mblk of 16 nodes m, one batch b). Conv MFMA core (R11/R14
// verified math). Cross-k accumulation now in LDS zq (NOT registers -> no
// VGPR-cap spill):
//   k=0: z0[m0+ml][bl*768 + o*12 + t] bf16
//   k=1..4: zq[j][(k-1)*8 .. +8) <- packed nibbles; end: zq -> Zm contiguous.
__global__ __launch_bounds__(256, 2)
void zpack_kernel(const float* __restrict__ x, const u16* __restrict__ wbf,
                  u8* __restrict__ Zm, u16* __restrict__ z0, int b0, int ldz) {
    __shared__ u16 lh[192 * 72];    // [jj=(ml*12+t)][c]
    __shared__ u16 zt[16 * 770];    // [ml][o*12+t]
    __shared__ u8 zq[768 * 32];     // [j][32 B] accumulated k-planes
    const int m0 = blockIdx.x << 4;
    const int bl = blockIdx.y;
    const int b = b0 + bl;
    const int tid = threadIdx.x;
    const int w = tid >> 6, l = tid & 63;

    // stage x -> lh bf16 (16 lanes x 48-B = 768-B contiguous runs)
    {
        int ml = tid & 15;
        int c = tid >> 4;
#pragma unroll
        for (int p = 0; p < 4; ++p, c += 16) {
            const float* src = x + ((size_t)(b * 64 + c) * 2048 + m0 + ml) * 12;
            float4 v0 = *(const float4*)(src + 0);
            float4 v1 = *(const float4*)(src + 4);
            float4 v2 = *(const float4*)(src + 8);
            float vv[12];
            *(float4*)&vv[0] = v0; *(float4*)&vv[4] = v1; *(float4*)&vv[8] = v2;
            u16* d = &lh[(ml * 12) * 72 + c];
#pragma unroll
            for (int t = 0; t < 12; ++t) d[t * 72] = f2bf(vv[t]);
        }
    }
    __syncthreads();

#pragma unroll
    for (int k = 0; k < 5; ++k) {
        f32x4 acc[4][3] = {};
#pragma unroll
        for (int kk = 0; kk < 2; ++kk) {
            bf16x8 wf[4], hf[3];
#pragma unroll
            for (int i = 0; i < 4; ++i)
                wf[i] = *(const bf16x8*)&wbf[(size_t)(k * 64 + i * 16 + (l & 15)) * 64 + kk * 32 + (l >> 4) * 8];
#pragma unroll
            for (int j = 0; j < 3; ++j)
                hf[j] = *(const bf16x8*)&lh[(w * 48 + j * 16 + (l & 15)) * 72 + kk * 32 + (l >> 4) * 8];
#pragma unroll
            for (int i = 0; i < 4; ++i)
#pragma unroll
                for (int j = 0; j < 3; ++j)
                    acc[i][j] = __builtin_amdgcn_mfma_f32_16x16x32_bf16(wf[i], hf[j], acc[i][j], 0, 0, 0);
        }
        __syncthreads();
        {
            const int lr = (l >> 4) * 4, lc = l & 15;
#pragma unroll
            for (int j = 0; j < 3; ++j) {
                int jj = w * 48 + j * 16 + lc;
                int ml = jj / 12, t = jj - ml * 12;
#pragma unroll
                for (int i = 0; i < 4; ++i)
#pragma unroll
                    for (int q = 0; q < 4; ++q)
                        zt[ml * 770 + (i * 16 + lr + q) * 12 + t] = f2bf(acc[i][j][q]);
            }
        }
        __syncthreads();
        if (k == 0) {
            for (int it = tid; it < 1536; it += 256) {   // 16 ml x 96 x (8 u16)
                int ml = it / 96, ch = it - ml * 96;
                *(u16x8*)&z0[(size_t)(m0 + ml) * ldz + bl * 768 + ch * 8] =
                    *(const u16x8*)&zt[ml * 770 + ch * 8];
            }
        } else {
#pragma unroll
            for (int jq = 0; jq < 3; ++jq) {
                int j = jq * 256 + tid;
                u32 lo = 0, hi = 0;
#pragma unroll
                for (int mp = 0; mp < 8; ++mp) {
                    u32 a = f2fp4(bf2f(zt[(2 * mp) * 770 + j]) * ZSCALE);
                    u32 bq = f2fp4(bf2f(zt[(2 * mp + 1) * 770 + j]) * ZSCALE);
                    u32 nib = a | (bq << 4);
                    if (mp < 4) lo |= nib << (8 * mp);
                    else        hi |= nib << (8 * (mp - 4));
                }
                uint2 v; v.x = lo; v.y = hi;
                *(uint2*)&zq[j * 32 + (k - 1) * 8] = v;   // LDS, not registers
            }
        }
        __syncthreads();   // zq/zt stable before next k overwrites zt
    }

    // zq -> Zm: 768 x 32 B fully contiguous, 16 B per iteration-thread
    {
        size_t base = ((size_t)blockIdx.x * ldz + bl * 768) * 32;
        for (int it = tid; it < 1536; it += 256) {
            *(i32x4*)(Zm + base + (size_t)it * 16) = *(const i32x4*)&zq[it * 16];
        }
    }
}

// ---------------------------------------------------------------------------
// 128^2-tile MX-fp4 GEMM, bf16 out (A^2 path; R9-R13 verified).
__global__ __launch_bounds__(256, 4)
void gemm_f4_kernel(const u8* __restrict__ A0, const u8* __restrict__ B0, u16* __restrict__ C0,
                    const u8* __restrict__ A1p, const u8* __restrict__ B1p, u16* __restrict__ C1p,
                    int Kb, int lda, int ldb, int ldc, float oscale) {
    const u8* A  = blockIdx.z ? A1p : A0;
    const u8* BT = blockIdx.z ? B1p : B0;
    u16* C       = blockIdx.z ? C1p : C0;

    __shared__ u8 lA[128 * 128];
    __shared__ u8 lB[128 * 128];

    int gx = gridDim.x;
    int nwg = gx * gridDim.y;
    int orig = blockIdx.y * gx + blockIdx.x;
    int swz = (orig & 7) * (nwg >> 3) + (orig >> 3);
    int by = swz / gx, bx = swz - by * gx;

    const int m0 = by * 128, n0 = bx * 128;
    const int tid = threadIdx.x;
    const int w = tid >> 6, l = tid & 63;
    const int wr = w >> 1, wc = w & 1;

    f32x4 acc[4][4] = {};

    const int srow = l >> 3;
    const int scol = ((l & 7) ^ srow) << 4;

    for (int kt = 0; kt < Kb; kt += 128) {
#pragma unroll
        for (int r = 0; r < 4; ++r) {
            int s = w * 4 + r;
            int row = s * 8 + srow;
            gload16(A + (size_t)(m0 + row) * lda + kt + scol, &lA[s * 1024]);
        }
#pragma unroll
        for (int r = 0; r < 4; ++r) {
            int s = w * 4 + r;
            int row = s * 8 + srow;
            gload16(BT + (size_t)(n0 + row) * ldb + kt + scol, &lB[s * 1024]);
        }
        __syncthreads();
#pragma unroll
        for (int kk = 0; kk < 2; ++kk) {
            i32x4 af[4], bfr[4];
            const int slot = kk * 4 + (l >> 4);
#pragma unroll
            for (int i = 0; i < 4; ++i) {
                int r = wr * 64 + i * 16 + (l & 15);
                af[i] = *(const i32x4*)&lA[(size_t)r * 128 + ((slot ^ (r & 7)) << 4)];
            }
#pragma unroll
            for (int j = 0; j < 4; ++j) {
                int r = wc * 64 + j * 16 + (l & 15);
                bfr[j] = *(const i32x4*)&lB[(size_t)r * 128 + ((slot ^ (r & 7)) << 4)];
            }
#pragma unroll
            for (int i = 0; i < 4; ++i)
#pragma unroll
                for (int j = 0; j < 4; ++j)
                    acc[i][j] = __builtin_amdgcn_mfma_scale_f32_16x16x128_f8f6f4(
                        up8(af[i]), up8(bfr[j]), acc[i][j], 4, 4, 0, 0x7F7F7F7F, 0, 0x7F7F7F7F);
        }
        __syncthreads();
    }

    const int lr = (l >> 4) * 4, lc = l & 15;
#pragma unroll
    for (int i = 0; i < 4; ++i) {
        int row = m0 + wr * 64 + i * 16 + lr;
#pragma unroll
        for (int j = 0; j < 4; ++j) {
            int col = n0 + wc * 64 + j * 16 + lc;
            u16* p = C + (size_t)row * ldc + col;
#pragma unroll
            for (int q = 0; q < 4; ++q)
                p[(size_t)q * ldc] = f2bf(acc[i][j][q] * oscale);
        }
    }
}

// ---------------------------------------------------------------------------
// Main GEMM with fused y epilogue: y = acc/32768 + z0 + bias.
// M=2048 (nodes), N=Gb*768 (j=bl*768+o*12+t), K=8192 (Kb=4096 A-bytes).
// B operand gathered from Zm block-K layout; 2D XCD chunk swizzle.
__global__ __launch_bounds__(256, 4)
void gemm_f4y_kernel(const u8* __restrict__ A, const u8* __restrict__ Zm,
                     const u16* __restrict__ z0, const float* __restrict__ bias,
                     float* __restrict__ y, int Kb, int lda, int ldj, int b0) {
    __shared__ u8 lA[128 * 128];
    __shared__ u8 lB[128 * 128];

    int gx = gridDim.x, gy = gridDim.y;
    int nwg = gx * gy;
    int orig = blockIdx.y * gx + blockIdx.x;
    int bx, by;
    if ((gx & 3) == 0 && (gy & 1) == 0) {
        int wx = gx >> 2, wy = gy >> 1;
        int xcd = orig & 7;
        int idx = orig >> 3;
        bx = (xcd & 3) * wx + idx % wx;
        by = (xcd >> 2) * wy + idx / wx;
    } else {
        int swz = (orig & 7) * (nwg >> 3) + (orig >> 3);
        by = swz / gx; bx = swz - by * gx;
    }

    const int m0 = by * 128, n0 = bx * 128;
    const int tid = threadIdx.x;
    const int w = tid >> 6, l = tid & 63;
    const int wr = w >> 1, wc = w & 1;

    f32x4 acc[4][4] = {};

    const int srow = l >> 3;
    const int scol = ((l & 7) ^ srow) << 4;
    const int mloc = scol >> 5;            // 0..3: mblk offset within K-tile
    const int half = scol & 16;            // 0 or 16 B within the 32-B chunk

    for (int kt = 0; kt < Kb; kt += 128) {
        const int ktm = kt >> 5;           // global mblk base of this K-tile
#pragma unroll
        for (int r = 0; r < 4; ++r) {
            int s = w * 4 + r;
            int row = s * 8 + srow;
            gload16(A + (size_t)(m0 + row) * lda + kt + scol, &lA[s * 1024]);
        }
#pragma unroll
        for (int r = 0; r < 4; ++r) {
            int s = w * 4 + r;
            int row = s * 8 + srow;
            gload16(Zm + ((size_t)(ktm + mloc) * ldj + (n0 + row)) * 32 + half, &lB[s * 1024]);
        }
        __syncthreads();
#pragma unroll
        for (int kk = 0; kk < 2; ++kk) {
            i32x4 af[4], bfr[4];
            const int slot = kk * 4 + (l >> 4);
#pragma unroll
            for (int i = 0; i < 4; ++i) {
                int r = wr * 64 + i * 16 + (l & 15);
                af[i] = *(const i32x4*)&lA[(size_t)r * 128 + ((slot ^ (r & 7)) << 4)];
            }
#pragma unroll
            for (int j = 0; j < 4; ++j) {
                int r = wc * 64 + j * 16 + (l & 15);
                bfr[j] = *(const i32x4*)&lB[(size_t)r * 128 + ((slot ^ (r & 7)) << 4)];
            }
#pragma unroll
            for (int i = 0; i < 4; ++i)
#pragma unroll
                for (int j = 0; j < 4; ++j)
                    acc[i][j] = __builtin_amdgcn_mfma_scale_f32_16x16x128_f8f6f4(
                        up8(af[i]), up8(bfr[j]), acc[i][j], 4, 4, 0, 0x7F7F7F7F, 0, 0x7F7F7F7F);
        }
        __syncthreads();
    }

    // epilogue: y[(b,o)][row*12+t] = acc/32768 + z0[row][col] + bias[o]
    const int lr = (l >> 4) * 4, lc = l & 15;
    const float os = 1.f / 32768.f;
#pragma unroll
    for (int j = 0; j < 4; ++j) {
        int col = n0 + wc * 64 + j * 16 + lc;
        int blv = col / 768;
        int r = col - blv * 768;
        int o = r / 12;
        int t = r - o * 12;
        float bv = bias[o];
        float* yb = y + ((size_t)((b0 + blv) * 64 + o) * 2048) * 12 + t;
#pragma unroll
        for (int i = 0; i < 4; ++i) {
            int row = m0 + wr * 64 + i * 16 + lr;
#pragma unroll
            for (int q = 0; q < 4; ++q) {
                float v = acc[i][j][q] * os + bf2f(z0[(size_t)(row + q) * ldj + col]) + bv;
                yb[(size_t)(row + q) * 12] = v;
            }
        }
    }
}

// ---------------------------------------------------------------------------
extern "C" void kernel_launch(void* const* d_in, const int* in_sizes, int n_in,
                              void* d_out, int out_size, void* d_ws, size_t ws_size,
                              hipStream_t stream) {
    (void)in_sizes; (void)n_in; (void)out_size;
    const float* x  = (const float*)d_in[0];
    const float* A1 = (const float*)d_in[1];
    const float* A2 = (const float*)d_in[2];
    const float* W  = (const float*)d_in[3];
    const float* bs = (const float*)d_in[4];
    float* y = (float*)d_out;
    char* ws = (char*)d_ws;

    const size_t CHUNK_OFF = 8454144;
    u8* ahat4 = (u8*)ws;
    u16* wbf = (u16*)(ws + 8388608);
    u8* a1p4 = (u8*)(ws + CHUNK_OFF);
    u8* a2p4 = a1p4 + (size_t)2048 * 1024;
    u8* a1t4 = a2p4 + (size_t)2048 * 1024;
    u8* a2t4 = a1t4 + (size_t)2048 * 1024;
    u16* a2sq = (u16*)(a2t4 + (size_t)2048 * 1024);   // [4096][2048] bf16

    // per-chunk bytes: Zm Gb*3145728 + z0 Gb*3145728
    size_t avail = ws_size > CHUNK_OFF ? ws_size - CHUNK_OFF : 0;
    int Gb = 16;
    while (Gb > 1 && (size_t)Gb * 6291456 > avail) Gb >>= 1;
    int ldj = Gb * 768;
    u8* Zm  = (u8*)(ws + CHUNK_OFF);
    u16* z0 = (u16*)(Zm + (size_t)128 * ldj * 32);

    cvt_w_kernel<<<80, 256, 0, stream>>>(W, wbf);
    cvt_a_kernel<<<2048, 256, 0, stream>>>(A1, A2, ahat4, a1p4, a2p4, a1t4, a2t4);

    // A1^2, A2^2 in fp4 (dual launch); acc = A^2 * 2^26 -> bf16 * 2^-26
    gemm_f4_kernel<<<dim3(16, 16, 2), 256, 0, stream>>>(
        a1p4, a1t4, a2sq,
        a2p4, a2t4, a2sq + (size_t)2048 * 2048,
        1024, 1024, 1024, 2048, 1.f / 67108864.f);
    pack_a2_kernel<<<4096, 256, 0, stream>>>(a2sq, ahat4);

    for (int b0 = 0; b0 < 16; b0 += Gb) {
        zpack_kernel<<<dim3(128, Gb), 256, 0, stream>>>(x, wbf, Zm, z0, b0, ldj);
        gemm_f4y_kernel<<<dim3(Gb * 6, 16), 256, 0, stream>>>(
            ahat4, Zm, z0, bs, y, 4096, 4096, ldj, b0);
    }
}

// Round 16
// 265.442 us; speedup vs baseline: 2.3909x; 1.3241x over previous
//
#include <hip/hip_runtime.h>
#include <hip/hip_fp8.h>

// SparseGraphConv: y = W @ concat([x, A1x, A1^2 x, A2 x, A2^2 x]) + b
// B=16, C=64, N=2048, T=12, C_OUT=64.
//
// R13 structure (verified 279 us) + branchless fp4 encoder:
//   1. cvt_a:   A1,A2 f32 -> fp4(x8192) rows of Astack4 + fp4 transposed (a1t4/a2t4)
//   2. gemm_f4(z=2): A1^2, A2^2 (fp4 math, scale 2^-26) -> a2sq bf16 temp
//   3. pack_a2: a2sq bf16 -> fp4(x8192) rows of Astack4
//   4. pack_x:  x -> XtT4[(bl*12+t)*64+c][n] fp4 + X0[n][btc] bf16 (hop-0)
//   5. gemm_f48: Y8 = fp8(256 * Astack4 @ XtT4^T / 8192); 2D-chunk XCD swizzle
//   6. conv:    5-hop MFMA; k=0 from X0 (bf16), k=1..4 from Y8 (fp8 decode /256)

typedef __attribute__((ext_vector_type(8))) __bf16 bf16x8;
typedef __attribute__((ext_vector_type(4))) float f32x4;
typedef __attribute__((ext_vector_type(4))) int i32x4;
typedef __attribute__((ext_vector_type(8))) int i32x8;
typedef __attribute__((ext_vector_type(8))) unsigned short u16x8;
typedef unsigned short u16;
typedef unsigned int u32;
typedef unsigned char u8;

__device__ __forceinline__ u16 f2bf(float f) {
    u32 u = __float_as_uint(f);
    u32 r = u + 0x7FFFu + ((u >> 16) & 1u);   // round-to-nearest-even
    return (u16)(r >> 16);
}

__device__ __forceinline__ float bf2f(u16 v) {
    return __uint_as_float((u32)v << 16);
}

__device__ __forceinline__ u8 f2fp8(float f) {
    __hip_fp8_e4m3 v(f);
    return *(u8*)&v;
}

// e2m1 nibble encode, bit-arithmetic (threshold-identical to the cmp-ladder:
// 0.25/0.75/1.25/1.75/2.5/3.5/5, ties round up). Levels {0,.5,1,1.5,2,3,4,6}.
// For m>=0.75: clamp to [1,6], add half-ulp at bit 21 -> c = 2*(E)+2+b.
__device__ __forceinline__ u32 f2fp4(float f) {
    u32 uf = __float_as_uint(f);
    u32 sg = (uf >> 31) << 3;
    float m = __uint_as_float(uf & 0x7FFFFFFFu);
    u32 small = (m >= 0.25f) ? 1u : 0u;
    u32 u = __float_as_uint(fminf(fmaxf(m, 1.0f), 6.0f)) + 0x00200000u;
    u32 big = 2u * ((u >> 23) - 127u) + 2u + ((u >> 22) & 1u);
    return sg | ((m < 0.75f) ? small : big);
}

// e4m3fn byte (value = Y*256) -> bf16 bits of Y (exponent re-bias folds /256)
__device__ __forceinline__ u16 fp8_to_bf16_div256(u32 b) {
    u32 e = (b >> 3) & 0xF;
    u16 r = (u16)(((b >> 7) << 15) | ((e + 112) << 7) | ((b & 7) << 4));
    return e ? r : (u16)0;
}

__device__ __forceinline__ void gload16(const void* g, void* l) {
    __builtin_amdgcn_global_load_lds((const __attribute__((address_space(1))) void*)g,
                                     (__attribute__((address_space(3))) void*)l, 16, 0, 0);
}

__device__ __forceinline__ i32x8 up8(i32x4 v) {
    i32x8 r = {v[0], v[1], v[2], v[3], 0, 0, 0, 0};
    return r;
}

#define ASCALE 8192.f

// ---------------------------------------------------------------------------
__global__ __launch_bounds__(256)
void cvt_w_kernel(const float* __restrict__ W, u16* __restrict__ wbf) {
    int i = blockIdx.x * 256 + threadIdx.x;
    if (i < 5 * 64 * 64) {
        int c = i & 63;
        int o = (i >> 6) & 63;
        int k = i >> 12;
        wbf[i] = f2bf(W[o * 320 + k * 64 + c]);
    }
}

// ---------------------------------------------------------------------------
__global__ __launch_bounds__(256)
void cvt_a_kernel(const float* __restrict__ A1, const float* __restrict__ A2,
                  u8* __restrict__ astack4, u8* __restrict__ a1t4, u8* __restrict__ a2t4) {
    __shared__ float lt[64][65];
    int bid = blockIdx.x;
    int mat = bid >> 10;
    int ti = bid & 1023;
    int tr = (ti >> 5) << 6;
    int tc = (ti & 31) << 6;
    const float* src = mat ? A2 : A1;
    u8* dst4 = astack4 + (size_t)(mat ? 4096 : 0) * 1024;
    u8* dstT4 = mat ? a2t4 : a1t4;
    int tid = threadIdx.x;
    int rr = tid >> 4;
    int cc = (tid & 15) << 2;
#pragma unroll
    for (int p = 0; p < 4; ++p) {
        int row = p * 16 + rr;
        float4 v = *(const float4*)&src[(size_t)(tr + row) * 2048 + tc + cc];
        u16 w4 = (u16)(f2fp4(v.x * ASCALE) | (f2fp4(v.y * ASCALE) << 4) |
                       (f2fp4(v.z * ASCALE) << 8) | (f2fp4(v.w * ASCALE) << 12));
        *(u16*)&dst4[(size_t)(tr + row) * 1024 + ((tc + cc) >> 1)] = w4;
        lt[row][cc + 0] = v.x; lt[row][cc + 1] = v.y;
        lt[row][cc + 2] = v.z; lt[row][cc + 3] = v.w;
    }
    __syncthreads();
#pragma unroll
    for (int p = 0; p < 4; ++p) {
        int row = p * 16 + rr;   // row of transposed tile = original col
        u16 w4 = (u16)(f2fp4(lt[cc + 0][row] * ASCALE) |
                       (f2fp4(lt[cc + 1][row] * ASCALE) << 4) |
                       (f2fp4(lt[cc + 2][row] * ASCALE) << 8) |
                       (f2fp4(lt[cc + 3][row] * ASCALE) << 12));
        *(u16*)&dstT4[(size_t)(tc + row) * 1024 + ((tr + cc) >> 1)] = w4;
    }
}

// ---------------------------------------------------------------------------
__global__ __launch_bounds__(256)
void pack_a2_kernel(const u16* __restrict__ a2sq, u8* __restrict__ astack4) {
    int i = blockIdx.x * 256 + threadIdx.x;
    int e = i << 3;
    int r = e >> 11, c = e & 2047;
    const u16* s = a2sq + ((size_t)r << 11) + c;
    u16x8 v = *(const u16x8*)s;
    u32 w = 0;
#pragma unroll
    for (int j = 0; j < 8; ++j)
        w |= f2fp4(bf2f(v[j]) * ASCALE) << (4 * j);
    int row = (r < 2048) ? (2048 + r) : (4096 + r);
    *(u32*)&astack4[(size_t)row * 1024 + (c >> 1)] = w;
}

// ---------------------------------------------------------------------------
__global__ __launch_bounds__(256)
void pack_x_kernel(const float* __restrict__ x, u8* __restrict__ XtT4,
                   u16* __restrict__ X0, int b0, int ldy) {
    __shared__ u16 lt[32][776];
    const int bl = blockIdx.x >> 6;
    const int n0 = (blockIdx.x & 63) << 5;
    const int tid = threadIdx.x;
    const int ng = tid & 31, c8 = tid >> 5;
#pragma unroll
    for (int it = 0; it < 8; ++it) {
        int c = it * 8 + c8;
        const float* src = x + ((size_t)((b0 + bl) * 64 + c) * 2048 + n0 + ng) * 12;
        float4 v0 = *(const float4*)(src + 0);
        float4 v1 = *(const float4*)(src + 4);
        float4 v2 = *(const float4*)(src + 8);
        float vv[12];
        *(float4*)&vv[0] = v0; *(float4*)&vv[4] = v1; *(float4*)&vv[8] = v2;
#pragma unroll
        for (int t = 0; t < 12; ++t)
            lt[ng][t * 64 + c] = f2bf(vv[t]);
    }
    __syncthreads();
    for (int i = tid; i < 3072; i += 256) {
        int r = i / 96, ch = i - r * 96;
        *(u16x8*)&X0[(size_t)(n0 + r) * ldy + bl * 768 + ch * 8] =
            *(const u16x8*)&lt[r][ch * 8];
    }
    for (int i = tid; i < 1536; i += 256) {
        int rr = i >> 1, q = i & 1;
        uint2 w;
        u32 lo = 0, hi = 0;
#pragma unroll
        for (int j = 0; j < 4; ++j) {
            lo |= f2fp4(bf2f(lt[q * 16 + 2 * j + 0][rr])) << (8 * j);
            lo |= f2fp4(bf2f(lt[q * 16 + 2 * j + 1][rr])) << (8 * j + 4);
            hi |= f2fp4(bf2f(lt[q * 16 + 8 + 2 * j + 0][rr])) << (8 * j);
            hi |= f2fp4(bf2f(lt[q * 16 + 8 + 2 * j + 1][rr])) << (8 * j + 4);
        }
        w.x = lo; w.y = hi;
        *(uint2*)&XtT4[(size_t)(bl * 768 + rr) * 1024 + (n0 >> 1) + q * 8] = w;
    }
}

// ---------------------------------------------------------------------------
// Unified 128^2-tile MX-fp4 GEMM, bf16 out (A^2 path; R9-R13 verified).
__global__ __launch_bounds__(256, 4)
void gemm_f4_kernel(const u8* __restrict__ A0, const u8* __restrict__ B0, u16* __restrict__ C0,
                    const u8* __restrict__ A1p, const u8* __restrict__ B1p, u16* __restrict__ C1p,
                    int Kb, int lda, int ldb, int ldc, float oscale) {
    const u8* A  = blockIdx.z ? A1p : A0;
    const u8* BT = blockIdx.z ? B1p : B0;
    u16* C       = blockIdx.z ? C1p : C0;

    __shared__ u8 lA[128 * 128];
    __shared__ u8 lB[128 * 128];

    int gx = gridDim.x;
    int nwg = gx * gridDim.y;
    int orig = blockIdx.y * gx + blockIdx.x;
    int swz = (orig & 7) * (nwg >> 3) + (orig >> 3);
    int by = swz / gx, bx = swz - by * gx;

    const int m0 = by * 128, n0 = bx * 128;
    const int tid = threadIdx.x;
    const int w = tid >> 6, l = tid & 63;
    const int wr = w >> 1, wc = w & 1;

    f32x4 acc[4][4] = {};

    const int srow = l >> 3;
    const int scol = ((l & 7) ^ srow) << 4;

    for (int kt = 0; kt < Kb; kt += 128) {
#pragma unroll
        for (int r = 0; r < 4; ++r) {
            int s = w * 4 + r;
            int row = s * 8 + srow;
            gload16(A + (size_t)(m0 + row) * lda + kt + scol, &lA[s * 1024]);
        }
#pragma unroll
        for (int r = 0; r < 4; ++r) {
            int s = w * 4 + r;
            int row = s * 8 + srow;
            gload16(BT + (size_t)(n0 + row) * ldb + kt + scol, &lB[s * 1024]);
        }
        __syncthreads();
#pragma unroll
        for (int kk = 0; kk < 2; ++kk) {
            i32x4 af[4], bfr[4];
            const int slot = kk * 4 + (l >> 4);
#pragma unroll
            for (int i = 0; i < 4; ++i) {
                int r = wr * 64 + i * 16 + (l & 15);
                af[i] = *(const i32x4*)&lA[(size_t)r * 128 + ((slot ^ (r & 7)) << 4)];
            }
#pragma unroll
            for (int j = 0; j < 4; ++j) {
                int r = wc * 64 + j * 16 + (l & 15);
                bfr[j] = *(const i32x4*)&lB[(size_t)r * 128 + ((slot ^ (r & 7)) << 4)];
            }
#pragma unroll
            for (int i = 0; i < 4; ++i)
#pragma unroll
                for (int j = 0; j < 4; ++j)
                    acc[i][j] = __builtin_amdgcn_mfma_scale_f32_16x16x128_f8f6f4(
                        up8(af[i]), up8(bfr[j]), acc[i][j], 4, 4, 0, 0x7F7F7F7F, 0, 0x7F7F7F7F);
        }
        __syncthreads();
    }

    const int lr = (l >> 4) * 4, lc = l & 15;
#pragma unroll
    for (int i = 0; i < 4; ++i) {
        int row = m0 + wr * 64 + i * 16 + lr;
#pragma unroll
        for (int j = 0; j < 4; ++j) {
            int col = n0 + wc * 64 + j * 16 + lc;
            u16* p = C + (size_t)row * ldc + col;
#pragma unroll
            for (int q = 0; q < 4; ++q)
                p[(size_t)q * ldc] = f2bf(acc[i][j][q] * oscale);
        }
    }
}

// ---------------------------------------------------------------------------
// Main GEMM, fp8 e4m3 out, 2D-chunk XCD swizzle (R13-verified: FETCH 392->76 MB).
__global__ __launch_bounds__(256, 4)
void gemm_f48_kernel(const u8* __restrict__ A, const u8* __restrict__ BT,
                     u8* __restrict__ C, int Kb, int lda, int ldb, int ldc, float oscale) {
    __shared__ u8 lA[128 * 128];
    __shared__ u8 lB[128 * 128];

    int gx = gridDim.x;
    int gy = gridDim.y;
    int nwg = gx * gy;
    int orig = blockIdx.y * gx + blockIdx.x;
    int bx, by;
    if ((gx & 3) == 0 && gy == 64) {
        int wx = gx >> 2;
        int xcd = orig & 7;
        int idx = orig >> 3;
        int cx = xcd & 3, cy = xcd >> 2;
        bx = cx * wx + idx % wx;
        by = cy * 32 + idx / wx;
    } else {
        int swz = (orig & 7) * (nwg >> 3) + (orig >> 3);
        by = swz / gx; bx = swz - by * gx;
    }

    const int m0 = by * 128, n0 = bx * 128;
    const int tid = threadIdx.x;
    const int w = tid >> 6, l = tid & 63;
    const int wr = w >> 1, wc = w & 1;

    f32x4 acc[4][4] = {};

    const int srow = l >> 3;
    const int scol = ((l & 7) ^ srow) << 4;

    for (int kt = 0; kt < Kb; kt += 128) {
#pragma unroll
        for (int r = 0; r < 4; ++r) {
            int s = w * 4 + r;
            int row = s * 8 + srow;
            gload16(A + (size_t)(m0 + row) * lda + kt + scol, &lA[s * 1024]);
        }
#pragma unroll
        for (int r = 0; r < 4; ++r) {
            int s = w * 4 + r;
            int row = s * 8 + srow;
            gload16(BT + (size_t)(n0 + row) * ldb + kt + scol, &lB[s * 1024]);
        }
        __syncthreads();
#pragma unroll
        for (int kk = 0; kk < 2; ++kk) {
            i32x4 af[4], bfr[4];
            const int slot = kk * 4 + (l >> 4);
#pragma unroll
            for (int i = 0; i < 4; ++i) {
                int r = wr * 64 + i * 16 + (l & 15);
                af[i] = *(const i32x4*)&lA[(size_t)r * 128 + ((slot ^ (r & 7)) << 4)];
            }
#pragma unroll
            for (int j = 0; j < 4; ++j) {
                int r = wc * 64 + j * 16 + (l & 15);
                bfr[j] = *(const i32x4*)&lB[(size_t)r * 128 + ((slot ^ (r & 7)) << 4)];
            }
#pragma unroll
            for (int i = 0; i < 4; ++i)
#pragma unroll
                for (int j = 0; j < 4; ++j)
                    acc[i][j] = __builtin_amdgcn_mfma_scale_f32_16x16x128_f8f6f4(
                        up8(af[i]), up8(bfr[j]), acc[i][j], 4, 4, 0, 0x7F7F7F7F, 0, 0x7F7F7F7F);
        }
        __syncthreads();
    }

    const int lr = (l >> 4) * 4, lc = l & 15;
#pragma unroll
    for (int i = 0; i < 4; ++i) {
        int row = m0 + wr * 64 + i * 16 + lr;
#pragma unroll
        for (int j = 0; j < 4; ++j) {
            int col = n0 + wc * 64 + j * 16 + lc;
            u8* p = C + (size_t)row * ldc + col;
#pragma unroll
            for (int q = 0; q < 4; ++q)
                p[(size_t)q * ldc] = f2fp8(acc[i][j][q] * oscale);
        }
    }
}

// ---------------------------------------------------------------------------
// conv: 5-hop MFMA. k=0 from X0 (bf16); k=1..4 from Y8 (fp8 decode /256).
// Block = 16 nodes x 1 batch; y-writes 64-B coalesced (R10-verified epilogue).
__global__ __launch_bounds__(256, 2)
void conv_kernel(const u16* __restrict__ X0, const u8* __restrict__ Y8,
                 const u16* __restrict__ Wbf, const float* __restrict__ bias,
                 float* __restrict__ yout, int b0, int ldy) {
    __shared__ u16 lh[192 * 72];
    const int n0 = blockIdx.x << 4;
    const int bl = blockIdx.y;
    const int b = b0 + bl;
    const int tid = threadIdx.x;
    const int w = tid >> 6, l = tid & 63;
    f32x4 acc[4][3] = {};

    for (int k = 0; k < 5; ++k) {
        __syncthreads();
        for (int it = tid; it < 1536; it += 256) {
            int e8 = it << 3;
            int c = e8 & 63;
            int jj = e8 >> 6;
            int nl = jj / 12;
            int t = jj - nl * 12;
            if (k == 0) {
                const u16* src = X0 + (size_t)(n0 + nl) * ldy + bl * 768 + t * 64 + c;
                *(u16x8*)&lh[jj * 72 + c] = *(const u16x8*)src;
            } else {
                const u8* src = Y8 + (size_t)((k - 1) * 2048 + n0 + nl) * ldy + bl * 768 + t * 64 + c;
                uint2 v = *(const uint2*)src;
                u16x8 o;
#pragma unroll
                for (int j = 0; j < 4; ++j) o[j] = fp8_to_bf16_div256((v.x >> (8 * j)) & 0xFF);
#pragma unroll
                for (int j = 0; j < 4; ++j) o[4 + j] = fp8_to_bf16_div256((v.y >> (8 * j)) & 0xFF);
                *(u16x8*)&lh[jj * 72 + c] = o;
            }
        }
        __syncthreads();
#pragma unroll
        for (int kk = 0; kk < 2; ++kk) {
            bf16x8 wf[4], hf[3];
#pragma unroll
            for (int i = 0; i < 4; ++i)
                wf[i] = *(const bf16x8*)&Wbf[(size_t)(k * 64 + i * 16 + (l & 15)) * 64 + kk * 32 + (l >> 4) * 8];
#pragma unroll
            for (int j = 0; j < 3; ++j)
                hf[j] = *(const bf16x8*)&lh[(w * 48 + j * 16 + (l & 15)) * 72 + kk * 32 + (l >> 4) * 8];
#pragma unroll
            for (int i = 0; i < 4; ++i)
#pragma unroll
                for (int j = 0; j < 3; ++j)
                    acc[i][j] = __builtin_amdgcn_mfma_f32_16x16x32_bf16(wf[i], hf[j], acc[i][j], 0, 0, 0);
        }
    }

    const int lr = (l >> 4) * 4, lc = l & 15;
    float* ybase = yout + (size_t)b * 64 * 24576 + (size_t)n0 * 12;
#pragma unroll
    for (int i = 0; i < 4; ++i) {
#pragma unroll
        for (int q = 0; q < 4; ++q) {
            int o = i * 16 + lr + q;
            float bv = bias[o];
            float* yo = ybase + (size_t)o * 24576;
#pragma unroll
            for (int j = 0; j < 3; ++j) {
                int jj = w * 48 + j * 16 + lc;
                yo[jj] = acc[i][j][q] + bv;
            }
        }
    }
}

// ---------------------------------------------------------------------------
extern "C" void kernel_launch(void* const* d_in, const int* in_sizes, int n_in,
                              void* d_out, int out_size, void* d_ws, size_t ws_size,
                              hipStream_t stream) {
    (void)in_sizes; (void)n_in; (void)out_size;
    const float* x  = (const float*)d_in[0];
    const float* A1 = (const float*)d_in[1];
    const float* A2 = (const float*)d_in[2];
    const float* W  = (const float*)d_in[3];
    const float* bs = (const float*)d_in[4];
    float* y = (float*)d_out;
    char* ws = (char*)d_ws;

    const size_t CHUNK_OFF = 8454144;
    u8* astack4 = (u8*)ws;
    u16* wbf = (u16*)(ws + 8388608);
    u8* a1t4 = (u8*)(ws + CHUNK_OFF);
    u8* a2t4 = a1t4 + (size_t)2048 * 1024;
    u16* a2sq = (u16*)(a2t4 + (size_t)2048 * 1024);

    // per-chunk bytes: XtT4 Gb*786432 + X0 Gb*3145728 + Y8 Gb*6291456
    size_t avail = ws_size > CHUNK_OFF ? ws_size - CHUNK_OFF : 0;
    int Gb = 16;
    while (Gb > 1 && (size_t)Gb * 10223616 > avail) Gb >>= 1;
    int ldy = Gb * 768;
    u8* xtT4 = (u8*)(ws + CHUNK_OFF);
    u16* x0  = (u16*)(xtT4 + (size_t)Gb * 768 * 1024);
    u8* Y8   = (u8*)(x0 + (size_t)2048 * ldy);

    cvt_w_kernel<<<80, 256, 0, stream>>>(W, wbf);
    cvt_a_kernel<<<2048, 256, 0, stream>>>(A1, A2, astack4, a1t4, a2t4);

    gemm_f4_kernel<<<dim3(16, 16, 2), 256, 0, stream>>>(
        astack4, a1t4, a2sq,
        astack4 + (size_t)4096 * 1024, a2t4, a2sq + (size_t)2048 * 2048,
        1024, 1024, 1024, 2048, 1.f / 67108864.f);
    pack_a2_kernel<<<4096, 256, 0, stream>>>(a2sq, astack4);

    for (int b0 = 0; b0 < 16; b0 += Gb) {
        pack_x_kernel<<<Gb * 64, 256, 0, stream>>>(x, xtT4, x0, b0, ldy);
        gemm_f48_kernel<<<dim3(ldy / 128, 64), 256, 0, stream>>>(
            astack4, xtT4, Y8, 1024, 1024, 1024, ldy, 256.f / 8192.f);
        conv_kernel<<<dim3(128, Gb), 256, 0, stream>>>(x0, Y8, wbf, bs, y, b0, ldy);
    }
}